// Round 8
// baseline (615.172 us; speedup 1.0000x reference)
//
#include <hip/hip_runtime.h>

#define DD 32   // node/output dim
#define HH 64   // psi hidden
// PSI_IN = 5*32 = 160

#define HSTR 36   // bf16 stride for hdiff rows (72B rows; reads exactly 2-way = free)

typedef __attribute__((ext_vector_type(8))) short bf16x8;   // 8 bf16 = 4 VGPRs
typedef __attribute__((ext_vector_type(4))) float f32x4;

static __device__ __forceinline__ unsigned short f2bf(float x) {
    // round-to-nearest-even bf16 (inputs are finite; no NaN handling needed)
    union { float f; unsigned u; } v; v.f = x;
    unsigned r = (v.u + 0x7FFFu + ((v.u >> 16) & 1u)) >> 16;
    return (unsigned short)r;
}

static __device__ __forceinline__ float bf2f(unsigned short x) {
    union { unsigned u; float f; } v; v.u = ((unsigned)x) << 16;
    return v.f;
}

// Convert w0/w1/w2 to bf16 MFMA B-fragment order.
// 32 frags total: [0..19] = w0 (kk*4+t), [20..27] = w1 (kk*4+t), [28..31] = w2 (kk*2+t).
__global__ __launch_bounds__(256) void prep_weights(
    const float* __restrict__ w0, const float* __restrict__ w1,
    const float* __restrict__ w2, unsigned short* __restrict__ frags)
{
    const int tid = blockIdx.x * 256 + threadIdx.x;
    const int f = tid >> 6, l = tid & 63;
    if (f >= 32) return;
    const int c = l & 15, q = l >> 4;
    unsigned short* dst = frags + f * 512 + l * 8;
    if (f < 20) {
        const int kk = f >> 2, t = f & 3;
        const int n = t * 16 + c, kb = kk * 32 + q * 8;
        #pragma unroll
        for (int j = 0; j < 8; ++j) dst[j] = f2bf(w0[(kb + j) * HH + n]);
    } else if (f < 28) {
        const int f2 = f - 20, kk = f2 >> 2, t = f2 & 3;
        const int n = t * 16 + c, kb = kk * 32 + q * 8;
        #pragma unroll
        for (int j = 0; j < 8; ++j) dst[j] = f2bf(w1[(kb + j) * HH + n]);
    } else {
        const int f3 = f - 28, kk = f3 >> 1, t = f3 & 1;
        const int n = t * 16 + c, kb = kk * 32 + q * 8;
        #pragma unroll
        for (int j = 0; j < 8; ++j) dst[j] = f2bf(w2[(kb + j) * DD + n]);
    }
}

// Pack per-node features into ONE 128B bf16 row: npack[n] = [h_s[n][0..31] | h_d[n][0..31]].
__global__ __launch_bounds__(256) void pack_nodes(
    const float* __restrict__ h_d, const float* __restrict__ h_s,
    unsigned short* __restrict__ npack, int N)
{
    const int tid = blockIdx.x * 256 + threadIdx.x;   // one thread per 8 elems
    if (tid >= N * 8) return;
    const int n = tid >> 3, chunk = tid & 7;
    const float* src = (chunk < 4) ? (h_s + (size_t)n * DD + chunk * 8)
                                   : (h_d + (size_t)n * DD + (chunk - 4) * 8);
    const float4 v0 = ((const float4*)src)[0];
    const float4 v1 = ((const float4*)src)[1];
    unsigned short* dst = npack + (size_t)n * 64 + chunk * 8;
    dst[0] = f2bf(v0.x); dst[1] = f2bf(v0.y); dst[2] = f2bf(v0.z); dst[3] = f2bf(v0.w);
    dst[4] = f2bf(v1.x); dst[5] = f2bf(v1.y); dst[6] = f2bf(v1.z); dst[7] = f2bf(v1.w);
}

// Fused edge kernel tuned for 3 blocks/CU (24 waves/CU):
//  - LDS = w0+w1 frags (28KB) + swizzled xbuf (16KB) + bf16 hdiff (9KB) = 54272 B <= 54613
//  - only w2 frags in registers; __launch_bounds__(512,6) caps VGPR for 6 waves/SIMD
//  - xbuf stride 64 with XOR swizzle (idx ^ ((row&7)<<3)): conflict-free b128 reads
//  - hdiff: UNIFORM unsigned short access on both sides (u32-write/u16-read was UB -> NaN)
//  - receiver idx for epilogue via __shfl (no LDS stash)
__global__ __launch_bounds__(512, 6) void edge_mfma(
    const unsigned short* __restrict__ npack,
    const float* __restrict__ ef,
    const int* __restrict__ snd, const int* __restrict__ rcv,
    const unsigned short* __restrict__ frags,
    const float* __restrict__ b0, const float* __restrict__ b1,
    const float* __restrict__ b2,
    float* __restrict__ agg, int E, int ntiles)
{
    __shared__ __align__(16) unsigned short wlds[28 * 512];      // 28 KB: w0 + w1 frags
    __shared__ __align__(16) unsigned short xbuf[8][16 * 64];    // 16 KB: x1/x2 (swizzled)
    __shared__ __align__(16) unsigned short hdiff[8][16 * HSTR]; // 9 KB: bf16 h_dj - h_di

    const int lane = threadIdx.x & 63;
    const int w = threadIdx.x >> 6;          // wave in block, 0..7
    const int c = lane & 15, q = lane >> 4;

    // stage w0+w1 fragments to LDS (28 KB, coalesced; reads after __syncthreads)
    for (int i = threadIdx.x; i < 28 * 512 / 8; i += 512)
        ((float4*)wlds)[i] = ((const float4*)frags)[i];
    // w2 fragments in registers (16 VGPRs)
    bf16x8 wf2[4];
    #pragma unroll
    for (int t = 0; t < 4; ++t)
        wf2[t] = *(const bf16x8*)(frags + (28 + t) * 512 + lane * 8);
    __syncthreads();

    const float b0t[4] = {b0[c], b0[16 + c], b0[32 + c], b0[48 + c]};
    const float b1t[4] = {b1[c], b1[16 + c], b1[32 + c], b1[48 + c]};
    const float b2t[2] = {b2[c], b2[16 + c]};

    unsigned short* xb = xbuf[w];
    unsigned short* hd = hdiff[w];

    const int wave_id = blockIdx.x * 8 + w;
    const int nwaves = gridDim.x * 8;

    // prefetch first tile's indices (m = c = lane&15 is the edge row)
    int nsi = 0, nri = 0;
    if (wave_id < ntiles) {
        int e0 = wave_id * 16 + c; if (e0 >= E) e0 = E - 1;
        nsi = __builtin_nontemporal_load(snd + e0);
        nri = __builtin_nontemporal_load(rcv + e0);
    }

    for (int tile = wave_id; tile < ntiles; tile += nwaves) {
        const int base = tile * 16;
        const int si = nsi, ri = nri;
        {   // prefetch NEXT tile's indices: load latency hides under this tile's MLP
            const int nt = tile + nwaves;
            if (nt < ntiles) {
                int e2 = nt * 16 + c; if (e2 >= E) e2 = E - 1;
                nsi = __builtin_nontemporal_load(snd + e2);
                nri = __builtin_nontemporal_load(rcv + e2);
            }
        }
        int e = base + c; if (e >= E) e = E - 1;

        // ---- gather: 2 packed node rows + streaming ef (lane covers cols q*8..) ----
        const unsigned short* nps = npack + (size_t)si * 64 + q * 8;
        const unsigned short* npr = npack + (size_t)ri * 64 + q * 8;
        const bf16x8 a_ss = *(const bf16x8*)nps;          // h_s[sender]
        const bf16x8 a_sr = *(const bf16x8*)npr;          // h_s[receiver]
        const bf16x8 a_ds = *(const bf16x8*)(nps + 32);   // h_d[sender]
        const bf16x8 a_dr = *(const bf16x8*)(npr + 32);   // h_d[receiver]
        const f32x4 e0v = __builtin_nontemporal_load((const f32x4*)(ef + (size_t)e * DD + q * 8));
        const f32x4 e1v = __builtin_nontemporal_load((const f32x4*)(ef + (size_t)e * DD + q * 8) + 1);

        // stash bf16(h_dj - h_di) (row c, cols q*8..) — u16 stores, same type as reads
        #pragma unroll
        for (int j = 0; j < 8; ++j) {
            const float dv = bf2f((unsigned short)a_dr[j]) - bf2f((unsigned short)a_ds[j]);
            hd[c * HSTR + q * 8 + j] = f2bf(dv);
        }

        bf16x8 aef;
        aef[0] = (short)f2bf(e0v[0]); aef[1] = (short)f2bf(e0v[1]);
        aef[2] = (short)f2bf(e0v[2]); aef[3] = (short)f2bf(e0v[3]);
        aef[4] = (short)f2bf(e1v[0]); aef[5] = (short)f2bf(e1v[1]);
        aef[6] = (short)f2bf(e1v[2]); aef[7] = (short)f2bf(e1v[3]);

        // ---- layer 0: [16x160] @ [160x64], B-frags from LDS ----
        const bf16x8 af[5] = {a_ss, a_sr, a_ds, a_dr, aef};
        f32x4 c0[4] = {f32x4{0,0,0,0}, f32x4{0,0,0,0}, f32x4{0,0,0,0}, f32x4{0,0,0,0}};
        #pragma unroll
        for (int kk = 0; kk < 5; ++kk) {
            #pragma unroll
            for (int t = 0; t < 4; ++t) {
                const bf16x8 b = *(const bf16x8*)(wlds + (kk * 4 + t) * 512 + lane * 8);
                c0[t] = __builtin_amdgcn_mfma_f32_16x16x32_bf16(af[kk], b, c0[t], 0, 0, 0);
            }
        }
        // relu(C + b0) -> X1, swizzled store (row = q*4+r, col = t*16+c)
        #pragma unroll
        for (int t = 0; t < 4; ++t) {
            #pragma unroll
            for (int r = 0; r < 4; ++r) {
                const float v = fmaxf(c0[t][r] + b0t[t], 0.0f);
                const int row = q * 4 + r;
                xb[(row * 64 + t * 16 + c) ^ ((row & 7) << 3)] = f2bf(v);
            }
        }

        // ---- layer 1: [16x64] @ [64x64], A swizzled from LDS, B-frags from LDS ----
        f32x4 c1[4] = {f32x4{0,0,0,0}, f32x4{0,0,0,0}, f32x4{0,0,0,0}, f32x4{0,0,0,0}};
        #pragma unroll
        for (int kk = 0; kk < 2; ++kk) {
            const bf16x8 a = *(const bf16x8*)(xb + ((c * 64 + kk * 32 + q * 8) ^ ((c & 7) << 3)));
            #pragma unroll
            for (int t = 0; t < 4; ++t) {
                const bf16x8 b = *(const bf16x8*)(wlds + (20 + kk * 4 + t) * 512 + lane * 8);
                c1[t] = __builtin_amdgcn_mfma_f32_16x16x32_bf16(a, b, c1[t], 0, 0, 0);
            }
        }
        #pragma unroll
        for (int t = 0; t < 4; ++t) {
            #pragma unroll
            for (int r = 0; r < 4; ++r) {
                const float v = fmaxf(c1[t][r] + b1t[t], 0.0f);
                const int row = q * 4 + r;
                xb[(row * 64 + t * 16 + c) ^ ((row & 7) << 3)] = f2bf(v);
            }
        }

        // ---- layer 2: [16x64] @ [64x32], B from registers ----
        f32x4 c2[2] = {f32x4{0,0,0,0}, f32x4{0,0,0,0}};
        #pragma unroll
        for (int kk = 0; kk < 2; ++kk) {
            const bf16x8 a = *(const bf16x8*)(xb + ((c * 64 + kk * 32 + q * 8) ^ ((c & 7) << 3)));
            #pragma unroll
            for (int t = 0; t < 2; ++t)
                c2[t] = __builtin_amdgcn_mfma_f32_16x16x32_bf16(a, wf2[kk * 2 + t], c2[t], 0, 0, 0);
        }

        // ---- epilogue: s_ij = relu(psi)*(h_dj - h_di), scatter-add ----
        int rir[4];
        #pragma unroll
        for (int r = 0; r < 4; ++r) rir[r] = __shfl(ri, q * 4 + r);
        #pragma unroll
        for (int t = 0; t < 2; ++t) {
            const int h = t * 16 + c;               // C/D col = output dim
            #pragma unroll
            for (int r = 0; r < 4; ++r) {
                const int ee = base + q * 4 + r;    // C/D row = edge index
                if (ee < E) {
                    const float psi = fmaxf(c2[t][r] + b2t[t], 0.0f);
                    const float d = bf2f(hd[(q * 4 + r) * HSTR + h]);
                    atomicAdd(agg + (size_t)rir[r] * DD + h, psi * d);
                }
            }
        }
    }
}

// out[n][d] = h_d_prev[n][d] + sum_k agg[n][k] * W[k][d]
__global__ __launch_bounds__(256) void out_kernel(
    const float* __restrict__ h_d, const float* __restrict__ agg,
    const float* __restrict__ W, float* __restrict__ out, int N)
{
    const int idx = blockIdx.x * 256 + threadIdx.x;
    if (idx >= N * DD) return;
    const int n = idx >> 5;
    const int d = idx & 31;
    const float* arow = agg + (size_t)n * DD;
    float s = h_d[idx];
    #pragma unroll
    for (int k = 0; k < DD; ++k) s = fmaf(arow[k], W[k * DD + d], s);
    out[idx] = s;
}

extern "C" void kernel_launch(void* const* d_in, const int* in_sizes, int n_in,
                              void* d_out, int out_size, void* d_ws, size_t ws_size,
                              hipStream_t stream) {
    const float* h_d = (const float*)d_in[0];
    const float* h_s = (const float*)d_in[1];
    const float* ef  = (const float*)d_in[2];
    const int*   snd = (const int*)d_in[3];
    const int*   rcv = (const int*)d_in[4];
    const float* w0  = (const float*)d_in[5];
    const float* b0  = (const float*)d_in[6];
    const float* w1  = (const float*)d_in[7];
    const float* b1  = (const float*)d_in[8];
    const float* w2  = (const float*)d_in[9];
    const float* b2  = (const float*)d_in[10];
    const float* W   = (const float*)d_in[11];
    float* out = (float*)d_out;

    const int N = in_sizes[0] / DD;
    const int E = in_sizes[3];
    const int ntiles = (E + 15) / 16;

    // workspace layout (256B-aligned chunks)
    char* ws = (char*)d_ws;
    size_t off = 0;
    auto walloc = [&](size_t bytes) {
        char* ptr = ws + off; off += (bytes + 255) & ~(size_t)255; return ptr;
    };
    float* agg            = (float*)walloc((size_t)N * DD * sizeof(float));
    unsigned short* frags = (unsigned short*)walloc(32 * 512 * sizeof(unsigned short));
    unsigned short* npack = (unsigned short*)walloc((size_t)N * 64 * sizeof(unsigned short));

    (void)hipMemsetAsync(agg, 0, (size_t)N * DD * sizeof(float), stream);
    prep_weights<<<8, 256, 0, stream>>>(w0, w1, w2, frags);
    pack_nodes<<<(N * 8 + 255) / 256, 256, 0, stream>>>(h_d, h_s, npack, N);
    edge_mfma<<<768, 512, 0, stream>>>(npack, ef, snd, rcv, frags,
                                       b0, b1, b2, agg, E, ntiles);
    out_kernel<<<((N * DD) + 255) / 256, 256, 0, stream>>>(h_d, agg, W, out, N);
}

// Round 9
// 343.520 us; speedup vs baseline: 1.7908x; 1.7908x over previous
//
#include <hip/hip_runtime.h>

#define DD 32   // node/output dim
#define HH 64   // psi hidden
// PSI_IN = 5*32 = 160

#define DSTR 35   // f32 stride for hdiff rows

typedef __attribute__((ext_vector_type(8))) short bf16x8;   // 8 bf16 = 4 VGPRs
typedef __attribute__((ext_vector_type(4))) float f32x4;

static __device__ __forceinline__ unsigned short f2bf(float x) {
    // round-to-nearest-even bf16 (inputs are finite; no NaN handling needed)
    union { float f; unsigned u; } v; v.f = x;
    unsigned r = (v.u + 0x7FFFu + ((v.u >> 16) & 1u)) >> 16;
    return (unsigned short)r;
}

static __device__ __forceinline__ float bf2f(unsigned short x) {
    union { unsigned u; float f; } v; v.u = ((unsigned)x) << 16;
    return v.f;
}

// Convert w0/w1/w2 to bf16 MFMA B-fragment order.
// 32 frags total: [0..19] = w0 (kk*4+t), [20..27] = w1 (kk*4+t), [28..31] = w2 (kk*2+t).
__global__ __launch_bounds__(256) void prep_weights(
    const float* __restrict__ w0, const float* __restrict__ w1,
    const float* __restrict__ w2, unsigned short* __restrict__ frags)
{
    const int tid = blockIdx.x * 256 + threadIdx.x;
    const int f = tid >> 6, l = tid & 63;
    if (f >= 32) return;
    const int c = l & 15, q = l >> 4;
    unsigned short* dst = frags + f * 512 + l * 8;
    if (f < 20) {
        const int kk = f >> 2, t = f & 3;
        const int n = t * 16 + c, kb = kk * 32 + q * 8;
        #pragma unroll
        for (int j = 0; j < 8; ++j) dst[j] = f2bf(w0[(kb + j) * HH + n]);
    } else if (f < 28) {
        const int f2 = f - 20, kk = f2 >> 2, t = f2 & 3;
        const int n = t * 16 + c, kb = kk * 32 + q * 8;
        #pragma unroll
        for (int j = 0; j < 8; ++j) dst[j] = f2bf(w1[(kb + j) * HH + n]);
    } else {
        const int f3 = f - 28, kk = f3 >> 1, t = f3 & 1;
        const int n = t * 16 + c, kb = kk * 32 + q * 8;
        #pragma unroll
        for (int j = 0; j < 8; ++j) dst[j] = f2bf(w2[(kb + j) * DD + n]);
    }
}

// Pack per-node features into ONE 128B bf16 row: npack[n] = [h_s[n][0..31] | h_d[n][0..31]].
__global__ __launch_bounds__(256) void pack_nodes(
    const float* __restrict__ h_d, const float* __restrict__ h_s,
    unsigned short* __restrict__ npack, int N)
{
    const int tid = blockIdx.x * 256 + threadIdx.x;   // one thread per 8 elems
    if (tid >= N * 8) return;
    const int n = tid >> 3, chunk = tid & 7;
    const float* src = (chunk < 4) ? (h_s + (size_t)n * DD + chunk * 8)
                                   : (h_d + (size_t)n * DD + (chunk - 4) * 8);
    const float4 v0 = ((const float4*)src)[0];
    const float4 v1 = ((const float4*)src)[1];
    unsigned short* dst = npack + (size_t)n * 64 + chunk * 8;
    dst[0] = f2bf(v0.x); dst[1] = f2bf(v0.y); dst[2] = f2bf(v0.z); dst[3] = f2bf(v0.w);
    dst[4] = f2bf(v1.x); dst[5] = f2bf(v1.y); dst[6] = f2bf(v1.z); dst[7] = f2bf(v1.w);
}

// Fused edge kernel (R2 structure) + 2-deep gather pipeline:
// tile t+1's ten gather loads are issued BEFORE tile t's MLP, so their ~500-900cy
// latency hides under the 22 MFMAs; indices are prefetched two tiles ahead.
// w0+w1 B-frags in LDS (28KB); only w2 in registers -> room for the 24 prefetch
// VGPRs under __launch_bounds__(512,3) (cap ~170, no spill -- R8's (512,6) spilled).
__global__ __launch_bounds__(512, 3) void edge_mfma(
    const unsigned short* __restrict__ npack,
    const float* __restrict__ ef,
    const int* __restrict__ snd, const int* __restrict__ rcv,
    const unsigned short* __restrict__ frags,
    const float* __restrict__ b0, const float* __restrict__ b1,
    const float* __restrict__ b2,
    float* __restrict__ agg, int E, int ntiles)
{
    __shared__ __align__(16) unsigned short wlds[28 * 512];    // 28 KB: w0 + w1 frags
    __shared__ __align__(16) unsigned short xbuf[8][16 * 72];  // 18 KB: x1/x2 (stride 72)
    __shared__ float hdiff[8][16 * DSTR];                      // 17.5 KB -> 65 KB total (2 blk/CU)

    const int lane = threadIdx.x & 63;
    const int w = threadIdx.x >> 6;          // wave in block, 0..7
    const int c = lane & 15, q = lane >> 4;

    // stage w0+w1 fragments to LDS (28 KB, coalesced; sync before reads)
    for (int i = threadIdx.x; i < 28 * 512 / 8; i += 512)
        ((float4*)wlds)[i] = ((const float4*)frags)[i];
    // w2 fragments in registers (16 VGPRs)
    bf16x8 wf2[4];
    #pragma unroll
    for (int t = 0; t < 4; ++t)
        wf2[t] = *(const bf16x8*)(frags + (28 + t) * 512 + lane * 8);
    __syncthreads();

    const float b0t[4] = {b0[c], b0[16 + c], b0[32 + c], b0[48 + c]};
    const float b1t[4] = {b1[c], b1[16 + c], b1[32 + c], b1[48 + c]};
    const float b2t[2] = {b2[c], b2[16 + c]};

    unsigned short* xb = xbuf[w];
    float* hd = hdiff[w];

    const int wave_id = blockIdx.x * 8 + w;
    const int nwaves = gridDim.x * 8;

    // ---- pipeline prologue: gather tile0, prefetch tile1's indices ----
    int si0 = 0, ri0 = 0, si1 = 0, ri1 = 0;
    bf16x8 gss = {}, gsr = {}, gds = {}, gdr = {};
    f32x4 ge0 = {}, ge1 = {};
    if (wave_id < ntiles) {
        int e0 = wave_id * 16 + c; if (e0 >= E) e0 = E - 1;
        si0 = __builtin_nontemporal_load(snd + e0);
        ri0 = __builtin_nontemporal_load(rcv + e0);
        const unsigned short* nps = npack + (size_t)si0 * 64 + q * 8;
        const unsigned short* npr = npack + (size_t)ri0 * 64 + q * 8;
        gss = *(const bf16x8*)nps;        gsr = *(const bf16x8*)npr;
        gds = *(const bf16x8*)(nps + 32); gdr = *(const bf16x8*)(npr + 32);
        ge0 = __builtin_nontemporal_load((const f32x4*)(ef + (size_t)e0 * DD + q * 8));
        ge1 = __builtin_nontemporal_load((const f32x4*)(ef + (size_t)e0 * DD + q * 8) + 1);
        const int t1 = wave_id + nwaves;
        if (t1 < ntiles) {
            int e1 = t1 * 16 + c; if (e1 >= E) e1 = E - 1;
            si1 = __builtin_nontemporal_load(snd + e1);
            ri1 = __builtin_nontemporal_load(rcv + e1);
        }
    }

    for (int tile = wave_id; tile < ntiles; tile += nwaves) {
        const int nt = tile + nwaves;

        // ---- issue NEXT tile's gathers; latency hides under this tile's MLP ----
        bf16x8 nss = {}, nsr = {}, nds = {}, ndr = {};
        f32x4 ne0 = {}, ne1 = {};
        if (nt < ntiles) {
            const unsigned short* nps = npack + (size_t)si1 * 64 + q * 8;
            const unsigned short* npr = npack + (size_t)ri1 * 64 + q * 8;
            nss = *(const bf16x8*)nps;        nsr = *(const bf16x8*)npr;
            nds = *(const bf16x8*)(nps + 32); ndr = *(const bf16x8*)(npr + 32);
            int e = nt * 16 + c; if (e >= E) e = E - 1;
            ne0 = __builtin_nontemporal_load((const f32x4*)(ef + (size_t)e * DD + q * 8));
            ne1 = __builtin_nontemporal_load((const f32x4*)(ef + (size_t)e * DD + q * 8) + 1);
        }
        // ---- prefetch indices two tiles ahead ----
        int si2 = 0, ri2 = 0;
        const int t2 = nt + nwaves;
        if (t2 < ntiles) {
            int e2 = t2 * 16 + c; if (e2 >= E) e2 = E - 1;
            si2 = __builtin_nontemporal_load(snd + e2);
            ri2 = __builtin_nontemporal_load(rcv + e2);
        }

        // stash h_dj - h_di (f32, row c, cols q*8..) for the transposed epilogue
        #pragma unroll
        for (int j = 0; j < 8; ++j)
            hd[c * DSTR + q * 8 + j] =
                bf2f((unsigned short)gdr[j]) - bf2f((unsigned short)gds[j]);

        bf16x8 aef;
        aef[0] = (short)f2bf(ge0[0]); aef[1] = (short)f2bf(ge0[1]);
        aef[2] = (short)f2bf(ge0[2]); aef[3] = (short)f2bf(ge0[3]);
        aef[4] = (short)f2bf(ge1[0]); aef[5] = (short)f2bf(ge1[1]);
        aef[6] = (short)f2bf(ge1[2]); aef[7] = (short)f2bf(ge1[3]);

        // ---- layer 0: [16x160] @ [160x64], B-frags from LDS ----
        const bf16x8 af[5] = {gss, gsr, gds, gdr, aef};
        f32x4 c0[4] = {f32x4{0,0,0,0}, f32x4{0,0,0,0}, f32x4{0,0,0,0}, f32x4{0,0,0,0}};
        #pragma unroll
        for (int kk = 0; kk < 5; ++kk) {
            #pragma unroll
            for (int t = 0; t < 4; ++t) {
                const bf16x8 b = *(const bf16x8*)(wlds + (kk * 4 + t) * 512 + lane * 8);
                c0[t] = __builtin_amdgcn_mfma_f32_16x16x32_bf16(af[kk], b, c0[t], 0, 0, 0);
            }
        }
        // relu(C + b0) -> X1 (row = q*4+r = edge, col = t*16+c)
        #pragma unroll
        for (int t = 0; t < 4; ++t) {
            #pragma unroll
            for (int r = 0; r < 4; ++r) {
                const float v = fmaxf(c0[t][r] + b0t[t], 0.0f);
                xb[(q * 4 + r) * 72 + t * 16 + c] = f2bf(v);
            }
        }

        // ---- layer 1: [16x64] @ [64x64], B-frags from LDS ----
        f32x4 c1[4] = {f32x4{0,0,0,0}, f32x4{0,0,0,0}, f32x4{0,0,0,0}, f32x4{0,0,0,0}};
        #pragma unroll
        for (int kk = 0; kk < 2; ++kk) {
            const bf16x8 a = *(const bf16x8*)(xb + c * 72 + kk * 32 + q * 8);
            #pragma unroll
            for (int t = 0; t < 4; ++t) {
                const bf16x8 b = *(const bf16x8*)(wlds + (20 + kk * 4 + t) * 512 + lane * 8);
                c1[t] = __builtin_amdgcn_mfma_f32_16x16x32_bf16(a, b, c1[t], 0, 0, 0);
            }
        }
        #pragma unroll
        for (int t = 0; t < 4; ++t) {
            #pragma unroll
            for (int r = 0; r < 4; ++r) {
                const float v = fmaxf(c1[t][r] + b1t[t], 0.0f);
                xb[(q * 4 + r) * 72 + t * 16 + c] = f2bf(v);
            }
        }

        // ---- layer 2: [16x64] @ [64x32], B from registers ----
        f32x4 c2[2] = {f32x4{0,0,0,0}, f32x4{0,0,0,0}};
        #pragma unroll
        for (int kk = 0; kk < 2; ++kk) {
            const bf16x8 a = *(const bf16x8*)(xb + c * 72 + kk * 32 + q * 8);
            #pragma unroll
            for (int t = 0; t < 2; ++t)
                c2[t] = __builtin_amdgcn_mfma_f32_16x16x32_bf16(a, wf2[kk * 2 + t], c2[t], 0, 0, 0);
        }

        // ---- epilogue: s_ij = relu(psi)*(h_dj - h_di), scatter-add ----
        int rir[4];
        #pragma unroll
        for (int r = 0; r < 4; ++r) rir[r] = __shfl(ri0, q * 4 + r);
        #pragma unroll
        for (int t = 0; t < 2; ++t) {
            const int h = t * 16 + c;               // C/D col = output dim
            #pragma unroll
            for (int r = 0; r < 4; ++r) {
                const int ee = tile * 16 + q * 4 + r;   // C/D row = edge index
                if (ee < E) {
                    const float psi = fmaxf(c2[t][r] + b2t[t], 0.0f);
                    const float d = hd[(q * 4 + r) * DSTR + h];
                    atomicAdd(agg + (size_t)rir[r] * DD + h, psi * d);
                }
            }
        }

        // ---- rotate pipeline state ----
        gss = nss; gsr = nsr; gds = nds; gdr = ndr; ge0 = ne0; ge1 = ne1;
        si0 = si1; ri0 = ri1; si1 = si2; ri1 = ri2;
    }
}

// out[n][d] = h_d_prev[n][d] + sum_k agg[n][k] * W[k][d]
__global__ __launch_bounds__(256) void out_kernel(
    const float* __restrict__ h_d, const float* __restrict__ agg,
    const float* __restrict__ W, float* __restrict__ out, int N)
{
    const int idx = blockIdx.x * 256 + threadIdx.x;
    if (idx >= N * DD) return;
    const int n = idx >> 5;
    const int d = idx & 31;
    const float* arow = agg + (size_t)n * DD;
    float s = h_d[idx];
    #pragma unroll
    for (int k = 0; k < DD; ++k) s = fmaf(arow[k], W[k * DD + d], s);
    out[idx] = s;
}

extern "C" void kernel_launch(void* const* d_in, const int* in_sizes, int n_in,
                              void* d_out, int out_size, void* d_ws, size_t ws_size,
                              hipStream_t stream) {
    const float* h_d = (const float*)d_in[0];
    const float* h_s = (const float*)d_in[1];
    const float* ef  = (const float*)d_in[2];
    const int*   snd = (const int*)d_in[3];
    const int*   rcv = (const int*)d_in[4];
    const float* w0  = (const float*)d_in[5];
    const float* b0  = (const float*)d_in[6];
    const float* w1  = (const float*)d_in[7];
    const float* b1  = (const float*)d_in[8];
    const float* w2  = (const float*)d_in[9];
    const float* b2  = (const float*)d_in[10];
    const float* W   = (const float*)d_in[11];
    float* out = (float*)d_out;

    const int N = in_sizes[0] / DD;
    const int E = in_sizes[3];
    const int ntiles = (E + 15) / 16;

    // workspace layout (256B-aligned chunks)
    char* ws = (char*)d_ws;
    size_t off = 0;
    auto walloc = [&](size_t bytes) {
        char* ptr = ws + off; off += (bytes + 255) & ~(size_t)255; return ptr;
    };
    float* agg            = (float*)walloc((size_t)N * DD * sizeof(float));
    unsigned short* frags = (unsigned short*)walloc(32 * 512 * sizeof(unsigned short));
    unsigned short* npack = (unsigned short*)walloc((size_t)N * 64 * sizeof(unsigned short));

    (void)hipMemsetAsync(agg, 0, (size_t)N * DD * sizeof(float), stream);
    prep_weights<<<8, 256, 0, stream>>>(w0, w1, w2, frags);
    pack_nodes<<<(N * 8 + 255) / 256, 256, 0, stream>>>(h_d, h_s, npack, N);
    edge_mfma<<<512, 512, 0, stream>>>(npack, ef, snd, rcv, frags,
                                       b0, b1, b2, agg, E, ntiles);
    out_kernel<<<((N * DD) + 255) / 256, 256, 0, stream>>>(h_d, agg, W, out, N);
}